// Round 4
// baseline (135.480 us; speedup 1.0000x reference)
//
#include <hip/hip_runtime.h>

// Problem constants (from reference): B=4096, V=64 (variables), F=128 (factors), HO=3
constexpr int Bn  = 4096;
constexpr int Vn  = 64;
constexpr int Fn  = 128;
constexpr int NPB = Vn * Fn;   // 8192 elements per batch slice

typedef float f32x4 __attribute__((ext_vector_type(4)));

// Insert x (row r) into a descending top-3 (w0>=w1>=w2); packed idx pk: bits
// [5:0]=i0 [11:6]=i1 [17:12]=i2. Rows are visited in ascending order, so
// strict '>' keeps the earlier (lower) row on ties == stable top_k.
__device__ __forceinline__ void ins3(float x, int r,
                                     float& w0, float& w1, float& w2, int& pk) {
    if (x > w0)      { w2 = w1; w1 = w0; w0 = x; pk = ((pk << 6) | r) & 0x3FFFF; }
    else if (x > w1) { w2 = w1; w1 = x;          pk = (pk & 0x3F) | (r << 6) | ((pk & 0xFC0) << 6); }
    else if (x > w2) { w2 = x;                   pk = (pk & 0xFFF) | (r << 12); }
}

// Tie-aware insert for cross-thread merges: (value desc, index asc) total order.
__device__ __forceinline__ void ins3t(float x, int r,
                                      float& w0, float& w1, float& w2,
                                      int& j0, int& j1, int& j2) {
    const bool b0 = (x > w0) || (x == w0 && r < j0);
    const bool b1 = (x > w1) || (x == w1 && r < j1);
    const bool b2 = (x > w2) || (x == w2 && r < j2);
    if (b0)      { w2 = w1; j2 = j1; w1 = w0; j1 = j0; w0 = x; j0 = r; }
    else if (b1) { w2 = w1; j2 = j1; w1 = x;  j1 = r; }
    else if (b2) { w2 = x;  j2 = r; }
}

// One block per batch b. No softmax LDS tile: with float4 loads, thread t
// always holds columns (4t)&127..+3 (row = t/32 + 8i), so top-3 runs in
// registers fused with the streaming loop. LDS = 8 KiB of per-wave partials.
__global__ __launch_bounds__(256)
void adj_generator_kernel(const float* __restrict__ sm_g,
                          float* __restrict__ out_sm,
                          float* __restrict__ out_adj,
                          float* __restrict__ out_ent) {
    const int b = blockIdx.x;
    const int t = threadIdx.x;

    __shared__ f32x4 part[4][Fn];              // per-wave partial top-3 per factor (8 KiB)
    __shared__ unsigned long long topm[Fn];    // per-factor chosen-variable bitmask
    __shared__ float wsum[4];                  // per-wave entropy partials

    const f32x4* s4 = (const f32x4*)(sm_g   + (size_t)b * NPB);
    f32x4*       o4 = (f32x4*)(out_sm + (size_t)b * NPB);

    float w0[4], w1[4], w2[4];
    int   pk[4];
    #pragma unroll
    for (int c = 0; c < 4; ++c) { w0[c] = w1[c] = w2[c] = -1e30f; pk[c] = 0; }

    unsigned int pred = 0;                     // (x > 0.01) bits, one per element
    float esum = 0.0f;
    const int rbase = t >> 5;                  // row = rbase + 8*i

    // ---- Phase 1: stream load + copy + entropy + fused per-column top-3 ----
    #pragma unroll
    for (int i = 0; i < 8; ++i) {
        const int idx = t + i * 256;
        const f32x4 v = __builtin_nontemporal_load(&s4[idx]);
        __builtin_nontemporal_store(v, &o4[idx]);   // softmax pass-through
        esum -= v.x * __logf(v.x) + v.y * __logf(v.y)
              + v.z * __logf(v.z) + v.w * __logf(v.w);
        pred |= ((v.x > 0.01f ? 1u : 0u) << (4*i    ))
              | ((v.y > 0.01f ? 1u : 0u) << (4*i + 1))
              | ((v.z > 0.01f ? 1u : 0u) << (4*i + 2))
              | ((v.w > 0.01f ? 1u : 0u) << (4*i + 3));
        const int r = rbase + 8 * i;
        ins3(v.x, r, w0[0], w1[0], w2[0], pk[0]);
        ins3(v.y, r, w0[1], w1[1], w2[1], pk[1]);
        ins3(v.z, r, w0[2], w1[2], w2[2], pk[2]);
        ins3(v.w, r, w0[3], w1[3], w2[3], pk[3]);
    }

    // ---- Pair-merge: lanes t <-> t^32 share columns, complementary rows ----
    const int wv   = t >> 6;
    const int col0 = (4 * t) & (Fn - 1);
    #pragma unroll
    for (int c = 0; c < 4; ++c) {
        const float p0 = __shfl_xor(w0[c], 32);
        const float p1 = __shfl_xor(w1[c], 32);
        const float p2 = __shfl_xor(w2[c], 32);
        const int   pp = __shfl_xor(pk[c], 32);
        int j0 = pk[c] & 63, j1 = (pk[c] >> 6) & 63, j2 = (pk[c] >> 12) & 63;
        ins3t(p0,  pp        & 63, w0[c], w1[c], w2[c], j0, j1, j2);
        ins3t(p1, (pp >> 6)  & 63, w0[c], w1[c], w2[c], j0, j1, j2);
        ins3t(p2, (pp >> 12) & 63, w0[c], w1[c], w2[c], j0, j1, j2);
        if ((t & 32) == 0) {
            f32x4 st;
            st.x = w0[c]; st.y = w1[c]; st.z = w2[c];
            st.w = __int_as_float(j0 | (j1 << 6) | (j2 << 12));
            part[wv][col0 + c] = st;
        }
    }

    // ---- Entropy wave reduction ----
    #pragma unroll
    for (int off = 32; off > 0; off >>= 1)
        esum += __shfl_down(esum, off);
    if ((t & 63) == 0) wsum[wv] = esum;

    __syncthreads();

    if (t == 0)
        out_ent[b] = (wsum[0] + wsum[1] + wsum[2] + wsum[3]) * (1.0f / Fn);

    // ---- Final 4-way merge + order selection -> bitmask (threads 0..127) ----
    if (t < Fn) {
        f32x4 a = part[0][t];
        float v0 = a.x, v1 = a.y, v2 = a.z;
        int p = __float_as_int(a.w);
        int i0 = p & 63, i1 = (p >> 6) & 63, i2 = (p >> 12) & 63;
        #pragma unroll
        for (int w = 1; w < 4; ++w) {
            const f32x4 q4 = part[w][t];
            const int q = __float_as_int(q4.w);
            ins3t(q4.x,  q        & 63, v0, v1, v2, i0, i1, i2);
            ins3t(q4.y, (q >> 6)  & 63, v0, v1, v2, i0, i1, i2);
            ins3t(q4.z, (q >> 12) & 63, v0, v1, v2, i0, i1, i2);
        }
        // Match numpy f32 evaluation order; no FMA contraction.
        const float p3  = __fmul_rn(__fmul_rn(v0, v0), v0);
        const float p2_ = __fmul_rn(__fmul_rn(__fmul_rn(3.0f, v1), v2), __fadd_rn(v1, v2));
        const float p1_ = __fmul_rn(__fmul_rn(__fmul_rn(6.0f, v0), v1), v2);
        const bool c3 = (p3  > p2_) && (p3  > p1_);
        const bool c2 = (p2_ >= p3) && (p2_ > p1_);
        const int  jj1 = c3 ? i0 : i1;
        const int  jj2 = (c3 || c2) ? i0 : i2;
        topm[t] = (1ull << i0) | (1ull << jj1) | (1ull << jj2);
    }
    __syncthreads();

    // ---- Phase 4: adj = pred-bit & mask-bit, pure store burst ----
    f32x4* a4 = (f32x4*)(out_adj + (size_t)b * NPB);
    const unsigned long long m0 = topm[col0 + 0];
    const unsigned long long m1 = topm[col0 + 1];
    const unsigned long long m2 = topm[col0 + 2];
    const unsigned long long m3 = topm[col0 + 3];
    #pragma unroll
    for (int i = 0; i < 8; ++i) {
        const int idx = t + i * 256;
        const int r   = rbase + 8 * i;
        f32x4 a;
        a.x = (((pred >> (4*i    )) & 1u) && ((m0 >> r) & 1ull)) ? 1.0f : 0.0f;
        a.y = (((pred >> (4*i + 1)) & 1u) && ((m1 >> r) & 1ull)) ? 1.0f : 0.0f;
        a.z = (((pred >> (4*i + 2)) & 1u) && ((m2 >> r) & 1ull)) ? 1.0f : 0.0f;
        a.w = (((pred >> (4*i + 3)) & 1u) && ((m3 >> r) & 1ull)) ? 1.0f : 0.0f;
        __builtin_nontemporal_store(a, &a4[idx]);
    }
}

extern "C" void kernel_launch(void* const* d_in, const int* in_sizes, int n_in,
                              void* d_out, int out_size, void* d_ws, size_t ws_size,
                              hipStream_t stream) {
    const float* softmax = (const float*)d_in[0];
    // d_in[1] (log_probs) unused: ent computed as -p*log(p) (error < 1e-6 abs).

    float* out     = (float*)d_out;
    float* out_sm  = out;                              // [B,V,F] f32
    float* out_adj = out + (size_t)Bn * NPB;           // [B,V,F] as f32 0/1
    float* out_ent = out + 2 * (size_t)Bn * NPB;       // [B]

    adj_generator_kernel<<<Bn, 256, 0, stream>>>(softmax, out_sm, out_adj, out_ent);
}

// Round 5
// 81.367 us; speedup vs baseline: 1.6650x; 1.6650x over previous
//
#include <hip/hip_runtime.h>

// Problem constants (from reference): B=4096, V=64 (variables), F=128 (factors), HO=3
constexpr int Bn  = 4096;
constexpr int Vn  = 64;
constexpr int Fn  = 128;
constexpr int NPB = Vn * Fn;   // 8192 elements per batch slice

typedef float f32x4 __attribute__((ext_vector_type(4)));
typedef unsigned long long u64;

// Branchless insert of key k into descending sorted triple (m0 >= m1 >= m2).
// Key = (float_bits << 6) | (63 ^ row): value desc, row asc on ties (stable top_k).
__device__ __forceinline__ void kins(u64 k, u64& m0, u64& m1, u64& m2) {
    const u64 a = m0 > k ? m0 : k;
    const u64 b = m0 > k ? k  : m0;
    m0 = a;
    const u64 c = m1 > b ? m1 : b;
    const u64 d = m1 > b ? b  : m1;
    m1 = c;
    m2 = m2 > d ? m2 : d;
}

// One block per batch b. No softmax LDS tile (R3's 32KiB -> 4 blocks/CU cap).
// Phase 1: stream f32x4 loads (cacheable) -> NT copy to out_sm + entropy + pred bits.
// Phase 3a: all 256 threads: col = t&127, rows (t>>7)*32..+31 re-read from GLOBAL
//           (L2-hot, just streamed), branchless u64-key top-3; partials -> LDS (6KiB).
// Phase 3b: threads 0..127 merge the 2 partials per column, order selection -> bitmask.
// Phase 4: adj = pred-bit & mask-bit, NT store burst.
__global__ __launch_bounds__(256)
void adj_generator_kernel(const float* __restrict__ sm_g,
                          float* __restrict__ out_sm,
                          float* __restrict__ out_adj,
                          float* __restrict__ out_ent) {
    const int b = blockIdx.x;
    const int t = threadIdx.x;

    __shared__ u64   parts[256][3];            // per-thread partial top-3 keys (6 KiB)
    __shared__ u64   topm[Fn];                 // per-factor chosen-variable bitmask
    __shared__ float wsum[4];                  // per-wave entropy partials

    const float* srow = sm_g + (size_t)b * NPB;
    const f32x4* s4   = (const f32x4*)srow;
    f32x4*       o4   = (f32x4*)(out_sm + (size_t)b * NPB);

    // ---- Phase 1: stream load + NT copy + entropy + pred bits ----
    unsigned int pred = 0;
    float esum = 0.0f;
    #pragma unroll
    for (int i = 0; i < 8; ++i) {
        const int idx = t + i * 256;
        const f32x4 v = s4[idx];                   // cacheable: phase 3a re-reads via L2
        __builtin_nontemporal_store(v, &o4[idx]);  // softmax pass-through
        esum -= v.x * __logf(v.x) + v.y * __logf(v.y)
              + v.z * __logf(v.z) + v.w * __logf(v.w);
        pred |= ((v.x > 0.01f ? 1u : 0u) << (4*i    ))
              | ((v.y > 0.01f ? 1u : 0u) << (4*i + 1))
              | ((v.z > 0.01f ? 1u : 0u) << (4*i + 2))
              | ((v.w > 0.01f ? 1u : 0u) << (4*i + 3));
    }

    // ---- Entropy wave reduction (write before barrier, final after) ----
    #pragma unroll
    for (int off = 32; off > 0; off >>= 1)
        esum += __shfl_down(esum, off);
    if ((t & 63) == 0) wsum[t >> 6] = esum;

    // ---- Phase 3a: branchless half-column scans from global (L2-hot) ----
    {
        const int c = t & (Fn - 1);
        const int h = t >> 7;                      // row half: 0 or 1
        const float* p = srow + (size_t)(h * 32) * Fn + c;
        u64 m0 = 0, m1 = 0, m2 = 0;
        #pragma unroll
        for (int r = 0; r < 32; ++r) {
            const float x = p[r * Fn];             // lanes contiguous -> coalesced
            const u64 k = ((u64)__float_as_uint(x) << 6) | (u64)(63 ^ (h * 32 + r));
            kins(k, m0, m1, m2);
        }
        parts[t][0] = m0; parts[t][1] = m1; parts[t][2] = m2;
    }
    __syncthreads();

    if (t == 0)
        out_ent[b] = (wsum[0] + wsum[1] + wsum[2] + wsum[3]) * (1.0f / Fn);

    // ---- Phase 3b: merge halves + order selection -> bitmask ----
    if (t < Fn) {
        u64 m0 = parts[t][0], m1 = parts[t][1], m2 = parts[t][2];
        kins(parts[t + 128][0], m0, m1, m2);
        kins(parts[t + 128][1], m0, m1, m2);
        kins(parts[t + 128][2], m0, m1, m2);
        const float v0 = __uint_as_float((unsigned)(m0 >> 6));
        const float v1 = __uint_as_float((unsigned)(m1 >> 6));
        const float v2 = __uint_as_float((unsigned)(m2 >> 6));
        const int   i0 = 63 ^ (int)(m0 & 63);
        const int   i1 = 63 ^ (int)(m1 & 63);
        const int   i2 = 63 ^ (int)(m2 & 63);
        // Match numpy f32 evaluation order; no FMA contraction.
        const float p3  = __fmul_rn(__fmul_rn(v0, v0), v0);
        const float p2_ = __fmul_rn(__fmul_rn(__fmul_rn(3.0f, v1), v2), __fadd_rn(v1, v2));
        const float p1_ = __fmul_rn(__fmul_rn(__fmul_rn(6.0f, v0), v1), v2);
        const bool c3 = (p3  > p2_) && (p3  > p1_);
        const bool c2 = (p2_ >= p3) && (p2_ > p1_);
        const int  j1 = c3 ? i0 : i1;
        const int  j2 = (c3 || c2) ? i0 : i2;
        topm[t] = (1ull << i0) | (1ull << j1) | (1ull << j2);
    }
    __syncthreads();

    // ---- Phase 4: adj = pred-bit & mask-bit, pure NT store burst ----
    f32x4* a4 = (f32x4*)(out_adj + (size_t)b * NPB);
    const int col0  = (4 * t) & (Fn - 1);
    const int rbase = t >> 5;
    const u64 m0 = topm[col0 + 0];
    const u64 m1 = topm[col0 + 1];
    const u64 m2 = topm[col0 + 2];
    const u64 m3 = topm[col0 + 3];
    #pragma unroll
    for (int i = 0; i < 8; ++i) {
        const int idx = t + i * 256;
        const int r   = rbase + 8 * i;
        f32x4 a;
        a.x = (((pred >> (4*i    )) & 1u) && ((m0 >> r) & 1ull)) ? 1.0f : 0.0f;
        a.y = (((pred >> (4*i + 1)) & 1u) && ((m1 >> r) & 1ull)) ? 1.0f : 0.0f;
        a.z = (((pred >> (4*i + 2)) & 1u) && ((m2 >> r) & 1ull)) ? 1.0f : 0.0f;
        a.w = (((pred >> (4*i + 3)) & 1u) && ((m3 >> r) & 1ull)) ? 1.0f : 0.0f;
        __builtin_nontemporal_store(a, &a4[idx]);
    }
}

extern "C" void kernel_launch(void* const* d_in, const int* in_sizes, int n_in,
                              void* d_out, int out_size, void* d_ws, size_t ws_size,
                              hipStream_t stream) {
    const float* softmax = (const float*)d_in[0];
    // d_in[1] (log_probs) unused: ent computed as -p*log(p) (error < 1e-6 abs).

    float* out     = (float*)d_out;
    float* out_sm  = out;                              // [B,V,F] f32
    float* out_adj = out + (size_t)Bn * NPB;           // [B,V,F] as f32 0/1
    float* out_ent = out + 2 * (size_t)Bn * NPB;       // [B]

    adj_generator_kernel<<<Bn, 256, 0, stream>>>(softmax, out_sm, out_adj, out_ent);
}

// Round 6
// 73.895 us; speedup vs baseline: 1.8334x; 1.1011x over previous
//
#include <hip/hip_runtime.h>

// Problem constants (from reference): B=4096, V=64 (variables), F=128 (factors), HO=3
constexpr int Bn  = 4096;
constexpr int Vn  = 64;
constexpr int Fn  = 128;
constexpr int NPB = Vn * Fn;   // 8192 elements per batch slice

typedef float f32x4 __attribute__((ext_vector_type(4)));
typedef unsigned long long u64;

// Branchless insert of key k into descending triple (m0 >= m1 >= m2).
// Key = (float_bits << 6) | (63 ^ row): value desc, row asc on ties (= stable
// top_k; keys are unique so merges in any order give the global top-3).
__device__ __forceinline__ void kins(u64 k, u64& m0, u64& m1, u64& m2) {
    const u64 a = m0 > k ? m0 : k;
    const u64 b = m0 > k ? k  : m0;
    m0 = a;
    const u64 c = m1 > b ? m1 : b;
    const u64 d = m1 > b ? b  : m1;
    m1 = c;
    m2 = m2 > d ? m2 : d;
}

// One block per batch b. Input read EXACTLY ONCE (no LDS tile, no re-read):
// with f32x4 loads, thread t always holds columns (4t)&127..+3 at row t>>5+8i,
// so a branchless in-register top-3 per column fuses into the streaming loop.
// Merge: shfl_xor(32) pairs lanes sharing columns, then 4-way wave merge in LDS.
__global__ __launch_bounds__(256)
void adj_generator_kernel(const float* __restrict__ sm_g,
                          float* __restrict__ out_sm,
                          float* __restrict__ out_adj,
                          float* __restrict__ out_ent) {
    const int b = blockIdx.x;
    const int t = threadIdx.x;

    __shared__ u64   part[3][4][Fn];           // per-wave partial top-3 keys (12 KiB)
    __shared__ u64   topm[Fn];                 // per-factor chosen-variable bitmask
    __shared__ float wsum[4];                  // per-wave entropy partials

    const f32x4* s4 = (const f32x4*)(sm_g   + (size_t)b * NPB);
    f32x4*       o4 = (f32x4*)(out_sm + (size_t)b * NPB);

    u64 m0[4], m1[4], m2[4];
    #pragma unroll
    for (int c = 0; c < 4; ++c) { m0[c] = 0; m1[c] = 0; m2[c] = 0; }

    unsigned int pred = 0;                     // (x > 0.01) bits
    float esum = 0.0f;
    const int rbase = t >> 5;                  // row = rbase + 8*i

    // ---- Phase 1: single-pass stream: load + NT copy + entropy + top-3 ----
    #pragma unroll
    for (int i = 0; i < 8; ++i) {
        const int idx = t + i * 256;
        const f32x4 v = __builtin_nontemporal_load(&s4[idx]);
        __builtin_nontemporal_store(v, &o4[idx]);   // softmax pass-through
        esum -= v.x * __logf(v.x) + v.y * __logf(v.y)
              + v.z * __logf(v.z) + v.w * __logf(v.w);
        pred |= ((v.x > 0.01f ? 1u : 0u) << (4*i    ))
              | ((v.y > 0.01f ? 1u : 0u) << (4*i + 1))
              | ((v.z > 0.01f ? 1u : 0u) << (4*i + 2))
              | ((v.w > 0.01f ? 1u : 0u) << (4*i + 3));
        const u64 rk = (u64)(63 ^ (rbase + 8 * i));
        kins(((u64)__float_as_uint(v.x) << 6) | rk, m0[0], m1[0], m2[0]);
        kins(((u64)__float_as_uint(v.y) << 6) | rk, m0[1], m1[1], m2[1]);
        kins(((u64)__float_as_uint(v.z) << 6) | rk, m0[2], m1[2], m2[2]);
        kins(((u64)__float_as_uint(v.w) << 6) | rk, m0[3], m1[3], m2[3]);
    }

    // ---- Pair-merge: lanes t <-> t^32 share columns, disjoint rows ----
    const int wv   = t >> 6;
    const int col0 = (4 * t) & (Fn - 1);
    #pragma unroll
    for (int c = 0; c < 4; ++c) {
        const u64 p0 = (u64)__shfl_xor((long long)m0[c], 32);
        const u64 p1 = (u64)__shfl_xor((long long)m1[c], 32);
        const u64 p2 = (u64)__shfl_xor((long long)m2[c], 32);
        kins(p0, m0[c], m1[c], m2[c]);
        kins(p1, m0[c], m1[c], m2[c]);
        kins(p2, m0[c], m1[c], m2[c]);
    }
    if ((t & 32) == 0) {
        #pragma unroll
        for (int c = 0; c < 4; ++c) {
            part[0][wv][col0 + c] = m0[c];
            part[1][wv][col0 + c] = m1[c];
            part[2][wv][col0 + c] = m2[c];
        }
    }

    // ---- Entropy wave reduction ----
    #pragma unroll
    for (int off = 32; off > 0; off >>= 1)
        esum += __shfl_down(esum, off);
    if ((t & 63) == 0) wsum[wv] = esum;

    __syncthreads();

    if (t == 0)
        out_ent[b] = (wsum[0] + wsum[1] + wsum[2] + wsum[3]) * (1.0f / Fn);

    // ---- Final 4-way merge + order selection -> bitmask (threads 0..127) ----
    if (t < Fn) {
        u64 k0 = part[0][0][t], k1 = part[1][0][t], k2 = part[2][0][t];
        #pragma unroll
        for (int w = 1; w < 4; ++w) {
            kins(part[0][w][t], k0, k1, k2);
            kins(part[1][w][t], k0, k1, k2);
            kins(part[2][w][t], k0, k1, k2);
        }
        const float v0 = __uint_as_float((unsigned)(k0 >> 6));
        const float v1 = __uint_as_float((unsigned)(k1 >> 6));
        const float v2 = __uint_as_float((unsigned)(k2 >> 6));
        const int   i0 = 63 ^ (int)(k0 & 63);
        const int   i1 = 63 ^ (int)(k1 & 63);
        const int   i2 = 63 ^ (int)(k2 & 63);
        // Match numpy f32 evaluation order; no FMA contraction.
        const float p3  = __fmul_rn(__fmul_rn(v0, v0), v0);
        const float p2_ = __fmul_rn(__fmul_rn(__fmul_rn(3.0f, v1), v2), __fadd_rn(v1, v2));
        const float p1_ = __fmul_rn(__fmul_rn(__fmul_rn(6.0f, v0), v1), v2);
        const bool c3 = (p3  > p2_) && (p3  > p1_);
        const bool c2 = (p2_ >= p3) && (p2_ > p1_);
        const int  j1 = c3 ? i0 : i1;
        const int  j2 = (c3 || c2) ? i0 : i2;
        topm[t] = (1ull << i0) | (1ull << j1) | (1ull << j2);
    }
    __syncthreads();

    // ---- Phase 4: adj = pred-bit & mask-bit, pure NT store burst ----
    f32x4* a4 = (f32x4*)(out_adj + (size_t)b * NPB);
    const u64 q0 = topm[col0 + 0];
    const u64 q1 = topm[col0 + 1];
    const u64 q2 = topm[col0 + 2];
    const u64 q3 = topm[col0 + 3];
    #pragma unroll
    for (int i = 0; i < 8; ++i) {
        const int idx = t + i * 256;
        const int r   = rbase + 8 * i;
        f32x4 a;
        a.x = (((pred >> (4*i    )) & 1u) && ((q0 >> r) & 1ull)) ? 1.0f : 0.0f;
        a.y = (((pred >> (4*i + 1)) & 1u) && ((q1 >> r) & 1ull)) ? 1.0f : 0.0f;
        a.z = (((pred >> (4*i + 2)) & 1u) && ((q2 >> r) & 1ull)) ? 1.0f : 0.0f;
        a.w = (((pred >> (4*i + 3)) & 1u) && ((q3 >> r) & 1ull)) ? 1.0f : 0.0f;
        __builtin_nontemporal_store(a, &a4[idx]);
    }
}

extern "C" void kernel_launch(void* const* d_in, const int* in_sizes, int n_in,
                              void* d_out, int out_size, void* d_ws, size_t ws_size,
                              hipStream_t stream) {
    const float* softmax = (const float*)d_in[0];
    // d_in[1] (log_probs) unused: ent computed as -p*log(p) (error < 1e-6 abs).

    float* out     = (float*)d_out;
    float* out_sm  = out;                              // [B,V,F] f32
    float* out_adj = out + (size_t)Bn * NPB;           // [B,V,F] as f32 0/1
    float* out_ent = out + 2 * (size_t)Bn * NPB;       // [B]

    adj_generator_kernel<<<Bn, 256, 0, stream>>>(softmax, out_sm, out_adj, out_ent);
}